// Round 3
// baseline (237.434 us; speedup 1.0000x reference)
//
#include <hip/hip_runtime.h>

// Multires hash-grid encode (2D, instant-NGP style). Round 6 (= round 5
// with the nontemporal-builtin compile fix: HIP_vector_type pointers are
// rejected; clang ext_vector_type floats are layout-identical and accepted).
//
// Evidence from round 4: level_pass re-fetches 152 MiB from HBM EVERY
// iteration although tables+x are only ~49 MiB — the 192 MiB/iter of
// streaming ws/out traffic thrashes L2+L3, so hashed gathers pay ~900-cyc
// HBM latency (VALU 11%, HBM 21%, occ 77% -> pure latency-bound).
//
// Changes:
//  (a) ALL streaming traffic (ws store/load, out store) is non-temporal:
//      keeps the 44.8 MiB tables + 4 MiB x resident in L2/L3 so gathers
//      become cache hits.
//  (b) level_pass processes 2 points/thread: 8 independent gathers in
//      flight per wave before any value is consumed (2x per-wave MLP).
//  XCD mapping (blockIdx%8 round-robins XCDs, each XCD owns one hashed
//  table) retained. Index math bit-exact vs jax reference.

static constexpr int  kPoints    = 524288;
static constexpr int  kLevels    = 16;
static constexpr int  kStartHash = 6;
static constexpr unsigned kPs1     = 19349663u;
static constexpr unsigned kEntries = 524309u;
static constexpr unsigned kR32     = 352277u;   // 2^32 mod kEntries

typedef float v2f __attribute__((ext_vector_type(2)));
typedef float v4f __attribute__((ext_vector_type(4)));

__device__ __forceinline__ void nt_store2(float2* p, const float2 v) {
    v2f t; t.x = v.x; t.y = v.y;
    __builtin_nontemporal_store(t, (v2f*)p);
}
__device__ __forceinline__ float2 nt_load2(const float2* p) {
    const v2f t = __builtin_nontemporal_load((const v2f*)p);
    return make_float2(t.x, t.y);
}
__device__ __forceinline__ void nt_store4(float4* p, const float4 v) {
    v4f t; t.x = v.x; t.y = v.y; t.z = v.z; t.w = v.w;
    __builtin_nontemporal_store(t, (v4f*)p);
}

__constant__ unsigned c_level_off[kLevels] = {
    0u, 289u, 1378u, 5603u, 22244u, 88293u, 351462u,
    875771u, 1400080u, 1924389u, 2448698u, 2973007u,
    3497316u, 4021625u, 4545934u, 5070243u
};

struct Corners {
    float    w00, w01, w10, w11;
    unsigned i00, i01, i10, i11;   // absolute table indices (level base folded in)
};

__device__ __forceinline__ Corners prep_level(const float2 p, const int l)
{
    const int   scale_i = 16 << l;
    const float scale_f = (float)scale_i;

    const float fx = p.x * scale_f;
    const float fy = p.y * scale_f;

    // coords in [0,1) -> indices nonnegative, max 524288 at level 15: u32 ok.
    const unsigned ix0 = (unsigned)(int)fx;
    const unsigned iy0 = (unsigned)(int)fy;
    const unsigned ix1 = (unsigned)(int)(fx + 1.0f);   // NOT always ix0+1 (fp rounding)
    const unsigned iy1 = (unsigned)(int)(fy + 1.0f);

    const float ox = fx - (float)ix0;
    const float oy = fy - (float)iy0;

    const float wx1 = fminf(fmaxf(ox, 0.0f), 1.0f);
    const float wx0 = fminf(fmaxf(1.0f - ox, 0.0f), 1.0f);
    const float wy1 = fminf(fmaxf(oy, 0.0f), 1.0f);
    const float wy0 = fminf(fmaxf(1.0f - oy, 0.0f), 1.0f);

    unsigned i00, i01, i10, i11;
    if (l < kStartHash) {
        const unsigned stride = (unsigned)(scale_i + 1);
        i00 = ix0 * stride + iy0;
        i01 = ix0 * stride + iy1;
        i10 = ix1 * stride + iy0;
        i11 = ix1 * stride + iy1;
    } else {
        // 32-bit replication of ((ix ^ (iy*PS1)) % E), bit-exact vs int64:
        // hy = iy*PS1 = hi*2^32+lo, hi <= 2362, ix < 2^20 so xor touches lo only.
        // (hi*2^32 + (lo^ix)) % E = ((hi*R32)%E + (lo^ix)%E) cond-sub E.
        const unsigned long long hy0 = (unsigned long long)iy0 * kPs1;
        const unsigned long long hy1 = (unsigned long long)iy1 * kPs1;
        const unsigned lo0 = (unsigned)hy0, hi0 = (unsigned)(hy0 >> 32);
        const unsigned lo1 = (unsigned)hy1, hi1 = (unsigned)(hy1 >> 32);
        const unsigned a0 = (hi0 * kR32) % kEntries;   // hi*R32 < 2^30
        const unsigned a1 = (hi1 * kR32) % kEntries;
        i00 = a0 + ((lo0 ^ ix0) % kEntries); if (i00 >= kEntries) i00 -= kEntries;
        i01 = a1 + ((lo1 ^ ix0) % kEntries); if (i01 >= kEntries) i01 -= kEntries;
        i10 = a0 + ((lo0 ^ ix1) % kEntries); if (i10 >= kEntries) i10 -= kEntries;
        i11 = a1 + ((lo1 ^ ix1) % kEntries); if (i11 >= kEntries) i11 -= kEntries;
    }

    Corners c;
    const unsigned base = c_level_off[l];
    c.i00 = base + i00; c.i01 = base + i01;
    c.i10 = base + i10; c.i11 = base + i11;
    c.w00 = wx0 * wy0;  c.w01 = wx0 * wy1;
    c.w10 = wx1 * wy0;  c.w11 = wx1 * wy1;
    return c;
}

__device__ __forceinline__ float2 finish_level(
    const Corners& c, const float2* __restrict__ tbl)
{
    const float2 v00 = tbl[c.i00];
    const float2 v01 = tbl[c.i01];
    const float2 v10 = tbl[c.i10];
    const float2 v11 = tbl[c.i11];
    return make_float2(
        c.w00 * v00.x + c.w01 * v01.x + c.w10 * v10.x + c.w11 * v11.x,
        c.w00 * v00.y + c.w01 * v01.y + c.w10 * v10.y + c.w11 * v11.y);
}

// ---- Pass 1: XCD-partitioned gather, 2 pts/thread, nt ws stores ---------
__global__ __launch_bounds__(256) void level_pass(
    const float2* __restrict__ x,
    const float2* __restrict__ tbl,
    float2* __restrict__ ws)
{
    const int b    = blockIdx.x;
    const int xcd  = b & 7;
    const int slot = b >> 3;        // 0..2047

    int level, pblk;                // pblk indexes 512-point superblocks
    if (slot < 1024) {
        level = 6 + xcd;            // hashed levels 6..13, one table per XCD
        pblk  = slot;
    } else if (slot < 1152) {
        level = 14;                 // split 8 ways
        pblk  = xcd * 128 + (slot - 1024);
    } else if (slot < 1280) {
        level = 15;                 // split 8 ways
        pblk  = xcd * 128 + (slot - 1152);
    } else {
        const int d = xcd * 768 + (slot - 1280);   // 0..6143
        level = d >> 10;            // dense levels 0..5
        pblk  = d & 1023;
    }

    const int n0 = (pblk << 9) | threadIdx.x;   // point A
    const int n1 = n0 + 256;                    // point B
    const float2 pA = x[n0];
    const float2 pB = x[n1];

    // Compute both address sets, then issue all 8 gathers back-to-back
    // before consuming any (8-deep MLP per lane).
    const Corners cA = prep_level(pA, level);
    const Corners cB = prep_level(pB, level);

    const float2 a00 = tbl[cA.i00], a01 = tbl[cA.i01];
    const float2 a10 = tbl[cA.i10], a11 = tbl[cA.i11];
    const float2 b00 = tbl[cB.i00], b01 = tbl[cB.i01];
    const float2 b10 = tbl[cB.i10], b11 = tbl[cB.i11];

    const float2 rA = make_float2(
        cA.w00 * a00.x + cA.w01 * a01.x + cA.w10 * a10.x + cA.w11 * a11.x,
        cA.w00 * a00.y + cA.w01 * a01.y + cA.w10 * a10.y + cA.w11 * a11.y);
    const float2 rB = make_float2(
        cB.w00 * b00.x + cB.w01 * b01.x + cB.w10 * b10.x + cB.w11 * b11.x,
        cB.w00 * b00.y + cB.w01 * b01.y + cB.w10 * b10.y + cB.w11 * b11.y);

    // tile-major ws[n>>8][16][256] float2; non-temporal: pure streaming,
    // keep it OUT of L2/L3 so the hash tables stay resident.
    const size_t tile0 = (size_t)(n0 >> 8);
    nt_store2(&ws[(tile0 << 12) + (level << 8) + (n0 & 255)], rA);
    nt_store2(&ws[((tile0 + 1) << 12) + (level << 8) + (n1 & 255)], rB);
}

// ---- Pass 2: LDS-tiled transpose ws[pblk][16][256] -> out[N][8] float4 --
static constexpr int kTStride = 257;  // float2 elems per level row in LDS

__global__ __launch_bounds__(256) void transpose_out(
    const float2* __restrict__ ws,
    float4* __restrict__ out)
{
    __shared__ float2 lds[kLevels * kTStride];  // ~32.9 KB

    const int t = threadIdx.x;
    const float2* __restrict__ tile = ws + ((size_t)blockIdx.x << 12);

#pragma unroll
    for (int l = 0; l < kLevels; ++l)
        lds[l * kTStride + t] = nt_load2(&tile[(l << 8) + t]);  // contiguous 32 KB

    __syncthreads();

    float4* o = out + ((size_t)blockIdx.x << 11);   // 256 pts * 8 float4
#pragma unroll
    for (int k = 0; k < 8; ++k) {
        const int f  = k * 256 + t;
        const int nl = f >> 3;       // local point
        const int i  = t & 7;        // float4 index within the 32-float row
        const float2 a = lds[(2 * i)     * kTStride + nl];
        const float2 b = lds[(2 * i + 1) * kTStride + nl];
        nt_store4(&o[f], make_float4(a.x, a.y, b.x, b.y));
    }
}

// ---- Fallback: single-pass (if ws too small) ----------------------------
__global__ __launch_bounds__(256) void hashgrid_fwd(
    const float2* __restrict__ x,
    const float2* __restrict__ tbl,
    float4* __restrict__ out)
{
    const int n = blockIdx.x * blockDim.x + threadIdx.x;
    if (n >= kPoints) return;
    const float2 p = x[n];
    float acc[2 * kLevels];
#pragma unroll
    for (int l = 0; l < kLevels; ++l) {
        const float2 r = finish_level(prep_level(p, l), tbl);
        acc[2 * l + 0] = r.x;
        acc[2 * l + 1] = r.y;
    }
    float4* o = out + (size_t)n * 8;
#pragma unroll
    for (int i = 0; i < 8; ++i)
        o[i] = make_float4(acc[4 * i + 0], acc[4 * i + 1],
                           acc[4 * i + 2], acc[4 * i + 3]);
}

extern "C" void kernel_launch(void* const* d_in, const int* in_sizes, int n_in,
                              void* d_out, int out_size, void* d_ws, size_t ws_size,
                              hipStream_t stream) {
    const float2* x   = (const float2*)d_in[0];
    const float2* tbl = (const float2*)d_in[1];

    const size_t ws_needed = (size_t)kLevels * kPoints * sizeof(float2); // 64 MiB
    if (ws_size >= ws_needed) {
        float2* ws = (float2*)d_ws;
        level_pass<<<kLevels * (kPoints / 512), 256, 0, stream>>>(x, tbl, ws);
        transpose_out<<<kPoints / 256, 256, 0, stream>>>(ws, (float4*)d_out);
    } else {
        hashgrid_fwd<<<kPoints / 256, 256, 0, stream>>>(x, tbl, (float4*)d_out);
    }
}